// Round 6
// baseline (2204.138 us; speedup 1.0000x reference)
//
#include <hip/hip_runtime.h>
#include <algorithm>

#define FIN 24
#define NHID 64
#define NMIX 216
#define NOUT 6
#define BN_EPS 1e-5f

// ---------- CSR build ----------
__global__ void k_hist(const int* __restrict__ ei, int E, int* deg) {
    int e = blockIdx.x * blockDim.x + threadIdx.x;
    if (e < E) atomicAdd(&deg[ei[E + e]], 1);
}

__global__ void k_dis(const int* __restrict__ deg, float* dis, int n) {
    int i = blockIdx.x * blockDim.x + threadIdx.x;
    if (i < n) { int v = deg[i]; dis[i] = v > 0 ? rsqrtf((float)v) : 0.f; }
}

// block-local exclusive scan over deg (n+1 elements, deg[i>=n]:=0); totals -> bsum
__global__ void k_scan_local(const int* __restrict__ deg, int n, int* rowptr, int* bsum) {
    __shared__ int s[256];
    int i = blockIdx.x * 256 + threadIdx.x;
    int v = (i < n) ? deg[i] : 0;
    s[threadIdx.x] = v;
    __syncthreads();
#pragma unroll
    for (int off = 1; off < 256; off <<= 1) {
        int x = (threadIdx.x >= off) ? s[threadIdx.x - off] : 0;
        __syncthreads();
        s[threadIdx.x] += x;
        __syncthreads();
    }
    if (i <= n) rowptr[i] = s[threadIdx.x] - v;  // exclusive
    if (threadIdx.x == 255) bsum[blockIdx.x] = s[255];
}

__global__ void k_scan_bsum(int* bsum, int nb) {
    __shared__ int s[256];
    int carry = 0;
    for (int base = 0; base < nb; base += 256) {
        int i = base + threadIdx.x;
        int v = (i < nb) ? bsum[i] : 0;
        s[threadIdx.x] = v;
        __syncthreads();
#pragma unroll
        for (int off = 1; off < 256; off <<= 1) {
            int x = (threadIdx.x >= off) ? s[threadIdx.x - off] : 0;
            __syncthreads();
            s[threadIdx.x] += x;
            __syncthreads();
        }
        if (i < nb) bsum[i] = s[threadIdx.x] - v + carry;
        carry += s[255];
        __syncthreads();
    }
}

__global__ void k_scan_add(int* rowptr, const int* __restrict__ bsum, int n) {
    int i = blockIdx.x * 256 + threadIdx.x;
    if (i <= n) rowptr[i] += bsum[blockIdx.x];
}

__global__ void k_fill(const int* __restrict__ ei, int E, const float* __restrict__ dis,
                       const int* __restrict__ rowptr, int* fill,
                       int* __restrict__ col, float* __restrict__ val) {
    int e = blockIdx.x * blockDim.x + threadIdx.x;
    if (e >= E) return;
    int s = ei[e], d = ei[E + e];
    int slot = rowptr[d] + atomicAdd(&fill[d], 1);
    col[slot] = s;
    val[slot] = -dis[s] * dis[d];
}

// ---------- gather prop, thread per dst node (full 24-float row) ----------
__global__ void k_propg(const int* __restrict__ rowptr, const int* __restrict__ col,
                        const float* __restrict__ val, float scale,
                        const float* __restrict__ h, const float* __restrict__ prev,
                        float* __restrict__ out, int n) {
    int t = blockIdx.x * blockDim.x + threadIdx.x;
    if (t >= n) return;
    int beg = rowptr[t], end = rowptr[t + 1];
    float4 a[6];
#pragma unroll
    for (int q = 0; q < 6; ++q) a[q] = make_float4(0.f, 0.f, 0.f, 0.f);
    for (int e = beg; e < end; ++e) {
        float w = val[e];
        const float4* hp = reinterpret_cast<const float4*>(h + (size_t)col[e] * FIN);
#pragma unroll
        for (int q = 0; q < 6; ++q) {
            float4 hv = hp[q];
            a[q].x = fmaf(w, hv.x, a[q].x);
            a[q].y = fmaf(w, hv.y, a[q].y);
            a[q].z = fmaf(w, hv.z, a[q].z);
            a[q].w = fmaf(w, hv.w, a[q].w);
        }
    }
    float4* op = reinterpret_cast<float4*>(out + (size_t)t * FIN);
    if (prev) {
        const float4* pp = reinterpret_cast<const float4*>(prev + (size_t)t * FIN);
#pragma unroll
        for (int q = 0; q < 6; ++q) {
            float4 pv = pp[q];
            op[q] = make_float4(fmaf(scale, a[q].x, -pv.x), fmaf(scale, a[q].y, -pv.y),
                                fmaf(scale, a[q].z, -pv.z), fmaf(scale, a[q].w, -pv.w));
        }
    } else {
#pragma unroll
        for (int q = 0; q < 6; ++q)
            op[q] = make_float4(scale * a[q].x, scale * a[q].y, scale * a[q].z, scale * a[q].w);
    }
}

// acc[node][j] (=|+=) S1@Wa + S2@Wb (+bias); lane=j, wave-uniform node.
// Software-pipelined: next node's rows prefetched into registers while
// current node's 96 FMAs execute; acc/bias base load issued early, added last.
__global__ void k_gemv2(const float* __restrict__ S1, const float* __restrict__ S2,
                        const float* __restrict__ Wa, const float* __restrict__ Wb,
                        const float* __restrict__ bias, float* __restrict__ acc,
                        float* __restrict__ stats, int n) {
    int j = threadIdx.x & 63;
    int grp = threadIdx.x >> 6;
    float wa[FIN], wb[FIN];
#pragma unroll
    for (int f = 0; f < FIN; ++f) wa[f] = Wa[f * NHID + j];
#pragma unroll
    for (int f = 0; f < FIN; ++f) wb[f] = Wb[f * NHID + j];
    const int stride = gridDim.x * 4;
    int node = blockIdx.x * 4 + grp;
    float sum = 0.f, sq = 0.f;
    float4 c1[6], c2[6];
    if (node < n) {
        const float4* r1 = reinterpret_cast<const float4*>(S1 + (size_t)node * FIN);
        const float4* r2 = reinterpret_cast<const float4*>(S2 + (size_t)node * FIN);
#pragma unroll
        for (int t = 0; t < 6; ++t) { c1[t] = r1[t]; c2[t] = r2[t]; }
    }
    while (node < n) {
        int nxt = node + stride;
        float4 d1[6], d2[6];
        if (nxt < n) {
            const float4* r1 = reinterpret_cast<const float4*>(S1 + (size_t)nxt * FIN);
            const float4* r2 = reinterpret_cast<const float4*>(S2 + (size_t)nxt * FIN);
#pragma unroll
            for (int t = 0; t < 6; ++t) { d1[t] = r1[t]; d2[t] = r2[t]; }
        }
        float base = bias ? bias[j] : acc[(size_t)node * NHID + j];  // issued here, used last
        float a = 0.f, p = 0.f;
#pragma unroll
        for (int t = 0; t < 6; ++t) {
            a = fmaf(c1[t].x, wa[t * 4 + 0], a);
            p = fmaf(c1[t].y, wa[t * 4 + 1], p);
            a = fmaf(c1[t].z, wa[t * 4 + 2], a);
            p = fmaf(c1[t].w, wa[t * 4 + 3], p);
        }
#pragma unroll
        for (int t = 0; t < 6; ++t) {
            a = fmaf(c2[t].x, wb[t * 4 + 0], a);
            p = fmaf(c2[t].y, wb[t * 4 + 1], p);
            a = fmaf(c2[t].z, wb[t * 4 + 2], a);
            p = fmaf(c2[t].w, wb[t * 4 + 3], p);
        }
        float r = base + a + p;
        acc[(size_t)node * NHID + j] = r;
        sum += r; sq = fmaf(r, r, sq);
#pragma unroll
        for (int t = 0; t < 6; ++t) { c1[t] = d1[t]; c2[t] = d2[t]; }
        node = nxt;
    }
    if (stats) {
        __shared__ float rs[256], rq[256];
        rs[threadIdx.x] = sum; rq[threadIdx.x] = sq;
        __syncthreads();
        if (threadIdx.x < 64) {
            float s = rs[threadIdx.x] + rs[threadIdx.x + 64] + rs[threadIdx.x + 128] + rs[threadIdx.x + 192];
            float q = rq[threadIdx.x] + rq[threadIdx.x + 64] + rq[threadIdx.x + 128] + rq[threadIdx.x + 192];
            atomicAdd(&stats[threadIdx.x], s);
            atomicAdd(&stats[NHID + threadIdx.x], q);
        }
    }
}

// BN coefficients for all 3 branches: scX[0:64]=scale, scX[64:128]=shift
__global__ void k_bnprep3(const float* __restrict__ st1, const float* __restrict__ g1,
                          const float* __restrict__ bt1, float inv1,
                          const float* __restrict__ st2, const float* __restrict__ g2,
                          const float* __restrict__ bt2, float inv2,
                          const float* __restrict__ st3, const float* __restrict__ g3,
                          const float* __restrict__ bt3, float inv3,
                          float* __restrict__ s1, float* __restrict__ s2,
                          float* __restrict__ s3) {
    int b = threadIdx.x >> 6, i = threadIdx.x & 63;
    const float* st = (b == 0) ? st1 : (b == 1) ? st2 : st3;
    const float* g  = (b == 0) ? g1  : (b == 1) ? g2  : g3;
    const float* bt = (b == 0) ? bt1 : (b == 1) ? bt2 : bt3;
    float inv       = (b == 0) ? inv1 : (b == 1) ? inv2 : inv3;
    float* so       = (b == 0) ? s1  : (b == 1) ? s2  : s3;
    float m = st[i] * inv;
    float v = st[NHID + i] * inv - m * m;
    float sc = g[i] * rsqrtf(v + BN_EPS);
    so[i] = sc;
    so[NHID + i] = fmaf(-m, sc, bt[i]);
}

// segment-mean scatter
__global__ void k_scatter(const float* __restrict__ x, const int* __restrict__ cl,
                          int n, float* xp, float* cnt) {
    int idx = blockIdx.x * blockDim.x + threadIdx.x;
    if (idx >= n * FIN) return;
    int node = idx / FIN, f = idx - node * FIN;
    int c = cl[node];
    atomicAdd(&xp[c * FIN + f], x[idx]);
    if (f == 0) atomicAdd(&cnt[c], 1.f);
}

__global__ void k_divcnt(float* xp, const float* __restrict__ cnt, int c) {
    int idx = blockIdx.x * blockDim.x + threadIdx.x;
    if (idx >= c * FIN) return;
    xp[idx] = xp[idx] / fmaxf(cnt[idx / FIN], 1.f);
}

// fused mix: thread per node; BN+ReLU for all three branches via precomputed
// scale/shift (uniform scalar loads); Wm/bm scalar-indexed.
__global__ void k_final(const float* __restrict__ acc1, const float* __restrict__ sc1,
                        const float* __restrict__ h2, const float* __restrict__ sc2,
                        const int* __restrict__ cl1,
                        const float* __restrict__ h3, const float* __restrict__ sc3,
                        const int* __restrict__ cl2,
                        const float* __restrict__ x, const float* __restrict__ Wm,
                        const float* __restrict__ bm, float* __restrict__ out, int n) {
    int t = blockIdx.x * blockDim.x + threadIdx.x;
    if (t >= n) return;
    float o[NOUT];
#pragma unroll
    for (int j = 0; j < NOUT; ++j) o[j] = bm[j];
    {
        const float4* r4 = reinterpret_cast<const float4*>(acc1 + (size_t)t * NHID);
#pragma unroll
        for (int i4 = 0; i4 < NHID / 4; ++i4) {
            float4 v = r4[i4];
            float hv[4] = {v.x, v.y, v.z, v.w};
#pragma unroll
            for (int c = 0; c < 4; ++c) {
                int i = i4 * 4 + c;
                float h = fmaxf(fmaf(hv[c], sc1[i], sc1[NHID + i]), 0.f);
#pragma unroll
                for (int j = 0; j < NOUT; ++j) o[j] = fmaf(h, Wm[i * NOUT + j], o[j]);
            }
        }
    }
    {
        const float4* r4 = reinterpret_cast<const float4*>(h2 + (size_t)cl1[t] * NHID);
#pragma unroll
        for (int i4 = 0; i4 < NHID / 4; ++i4) {
            float4 v = r4[i4];
            float hv[4] = {v.x, v.y, v.z, v.w};
#pragma unroll
            for (int c = 0; c < 4; ++c) {
                int hid = i4 * 4 + c;
                float h = fmaxf(fmaf(hv[c], sc2[hid], sc2[NHID + hid]), 0.f);
#pragma unroll
                for (int j = 0; j < NOUT; ++j) o[j] = fmaf(h, Wm[(NHID + hid) * NOUT + j], o[j]);
            }
        }
    }
    {
        const float4* r4 = reinterpret_cast<const float4*>(h3 + (size_t)cl2[t] * NHID);
#pragma unroll
        for (int i4 = 0; i4 < NHID / 4; ++i4) {
            float4 v = r4[i4];
            float hv[4] = {v.x, v.y, v.z, v.w};
#pragma unroll
            for (int c = 0; c < 4; ++c) {
                int hid = i4 * 4 + c;
                float h = fmaxf(fmaf(hv[c], sc3[hid], sc3[NHID + hid]), 0.f);
#pragma unroll
                for (int j = 0; j < NOUT; ++j) o[j] = fmaf(h, Wm[(2 * NHID + hid) * NOUT + j], o[j]);
            }
        }
    }
    {
        const float4* r4 = reinterpret_cast<const float4*>(x + (size_t)t * FIN);
#pragma unroll
        for (int i4 = 0; i4 < FIN / 4; ++i4) {
            float4 v = r4[i4];
            float hv[4] = {v.x, v.y, v.z, v.w};
#pragma unroll
            for (int c = 0; c < 4; ++c) {
                int i = 3 * NHID + i4 * 4 + c;
#pragma unroll
                for (int j = 0; j < NOUT; ++j) o[j] = fmaf(hv[c], Wm[i * NOUT + j], o[j]);
            }
        }
    }
    float* op = out + (size_t)t * NOUT;
#pragma unroll
    for (int j = 0; j < NOUT; ++j) op[j] = o[j];
}

extern "C" void kernel_launch(void* const* d_in, const int* in_sizes, int n_in,
                              void* d_out, int out_size, void* d_ws, size_t ws_size,
                              hipStream_t stream) {
    const int N = 200000, E = 800000;
    const int C1n = 20000, E1 = 80000;
    const int C2n = 2000, E2 = 8000;

    const float* x  = (const float*)d_in[0];
    const int* ei   = (const int*)d_in[1];
    const int* cl1  = (const int*)d_in[2];
    const int* cl2  = (const int*)d_in[3];
    const int* eic1 = (const int*)d_in[4];
    const int* eic2 = (const int*)d_in[5];
    const float* W1 = (const float*)d_in[6];  const float* b1 = (const float*)d_in[7];
    const float* g1 = (const float*)d_in[8];  const float* bt1 = (const float*)d_in[9];
    const float* W2 = (const float*)d_in[10]; const float* b2 = (const float*)d_in[11];
    const float* g2 = (const float*)d_in[12]; const float* bt2 = (const float*)d_in[13];
    const float* W3 = (const float*)d_in[14]; const float* b3 = (const float*)d_in[15];
    const float* g3 = (const float*)d_in[16]; const float* bt3 = (const float*)d_in[17];
    const float* Wm = (const float*)d_in[18]; const float* bm = (const float*)d_in[19];

    char* wb = (char*)d_ws;
    size_t off = 0;
    auto alloc = [&](size_t nwords) {
        void* p = wb + off; off += ((nwords + 3) & ~(size_t)3) * 4; return p;
    };
    // --- zero-region ---
    int* degi1 = (int*)alloc(N);   int* fill1 = (int*)alloc(N);
    int* degi2 = (int*)alloc(C1n); int* fill2 = (int*)alloc(C1n);
    int* degi3 = (int*)alloc(C2n); int* fill3 = (int*)alloc(C2n);
    float* st1 = (float*)alloc(128); float* st2 = (float*)alloc(128); float* st3 = (float*)alloc(128);
    float* xp1 = (float*)alloc((size_t)C1n * FIN); float* cnt1 = (float*)alloc(C1n);
    float* xp2 = (float*)alloc((size_t)C2n * FIN); float* cnt2 = (float*)alloc(C2n);
    size_t zero_bytes = off;
    // --- fully-overwritten region ---
    int* rp1 = (int*)alloc(N + 1);   int* col1 = (int*)alloc(E);  float* val1 = (float*)alloc(E);
    int* rp2 = (int*)alloc(C1n + 1); int* col2 = (int*)alloc(E1); float* val2 = (float*)alloc(E1);
    int* rp3 = (int*)alloc(C2n + 1); int* col3 = (int*)alloc(E2); float* val3 = (float*)alloc(E2);
    float* dis1 = (float*)alloc(N); float* dis2 = (float*)alloc(C1n); float* dis3 = (float*)alloc(C2n);
    int* bsum = (int*)alloc(1024);
    float* scsh1 = (float*)alloc(128); float* scsh2 = (float*)alloc(128); float* scsh3 = (float*)alloc(128);
    float* B1_0 = (float*)alloc((size_t)N * FIN);   float* B1_1 = (float*)alloc((size_t)N * FIN);
    float* B2_0 = (float*)alloc((size_t)C1n * FIN); float* B2_1 = (float*)alloc((size_t)C1n * FIN);
    float* B3_0 = (float*)alloc((size_t)C2n * FIN); float* B3_1 = (float*)alloc((size_t)C2n * FIN);
    float* acc1 = (float*)alloc((size_t)N * NHID);
    float* acc2 = (float*)alloc((size_t)C1n * NHID);
    float* acc3 = (float*)alloc((size_t)C2n * NHID);
    if (off > ws_size) return;  // fail visibly if ws too small

    hipMemsetAsync(d_ws, 0, zero_bytes, stream);

    const int T = 256;
    auto cdiv = [](int a, int b) { return (a + b - 1) / b; };

    auto branch = [&](const float* xin, int n, const int* e, int Ecnt,
                      const float* W, const float* bb, int* degi, int* fill, float* dis,
                      int* rp, int* col, float* val,
                      float* B0, float* Bb1, float* acc, float* st) {
        int ge = cdiv(Ecnt, T), gn = cdiv(n, T);
        int nb = cdiv(n + 1, 256);
        int gg = std::min(cdiv(n, 4), 1280);
        const int WSZ = FIN * NHID;
        // CSR build
        k_hist<<<ge, T, 0, stream>>>(e, Ecnt, degi);
        k_dis<<<gn, T, 0, stream>>>(degi, dis, n);
        k_scan_local<<<nb, 256, 0, stream>>>(degi, n, rp, bsum);
        k_scan_bsum<<<1, 256, 0, stream>>>(bsum, nb);
        k_scan_add<<<nb, 256, 0, stream>>>(rp, bsum, n);
        k_fill<<<ge, T, 0, stream>>>(e, Ecnt, dis, rp, fill, col, val);
        // Tx1 = P(x) -> B0
        k_propg<<<gn, T, 0, stream>>>(rp, col, val, 1.0f, xin, nullptr, B0, n);
        // acc = b + x@W0 + Tx1@W1
        k_gemv2<<<gg, T, 0, stream>>>(xin, B0, W, W + WSZ, bb, acc, nullptr, n);
        // Tx2 = 2P(Tx1) - x -> Bb1
        k_propg<<<gn, T, 0, stream>>>(rp, col, val, 2.0f, B0, xin, Bb1, n);
        // Tx3 = 2P(Tx2) - Tx1 -> B0 (in place over prev)
        k_propg<<<gn, T, 0, stream>>>(rp, col, val, 2.0f, Bb1, B0, B0, n);
        // acc += Tx2@W2 + Tx3@W3
        k_gemv2<<<gg, T, 0, stream>>>(Bb1, B0, W + 2 * WSZ, W + 3 * WSZ, nullptr, acc, nullptr, n);
        // Tx4 = 2P(Tx3) - Tx2 -> Bb1
        k_propg<<<gn, T, 0, stream>>>(rp, col, val, 2.0f, B0, Bb1, Bb1, n);
        // Tx5 = 2P(Tx4) - Tx3 -> B0
        k_propg<<<gn, T, 0, stream>>>(rp, col, val, 2.0f, Bb1, B0, B0, n);
        // acc += Tx4@W4 + Tx5@W5 (+BN stats)
        k_gemv2<<<gg, T, 0, stream>>>(Bb1, B0, W + 4 * WSZ, W + 5 * WSZ, nullptr, acc, st, n);
    };

    // branch 1: full graph
    branch(x, N, ei, E, W1, b1, degi1, fill1, dis1, rp1, col1, val1, B1_0, B1_1, acc1, st1);
    // branch 2
    k_scatter<<<cdiv(N * FIN, T), T, 0, stream>>>(x, cl1, N, xp1, cnt1);
    k_divcnt<<<cdiv(C1n * FIN, T), T, 0, stream>>>(xp1, cnt1, C1n);
    branch(xp1, C1n, eic1, E1, W2, b2, degi2, fill2, dis2, rp2, col2, val2, B2_0, B2_1, acc2, st2);
    // branch 3
    k_scatter<<<cdiv(N * FIN, T), T, 0, stream>>>(x, cl2, N, xp2, cnt2);
    k_divcnt<<<cdiv(C2n * FIN, T), T, 0, stream>>>(xp2, cnt2, C2n);
    branch(xp2, C2n, eic2, E2, W3, b3, degi3, fill3, dis3, rp3, col3, val3, B3_0, B3_1, acc3, st3);
    // BN coefficients for all three branches, then fused final mix
    k_bnprep3<<<1, 192, 0, stream>>>(st1, g1, bt1, 1.0f / (float)N,
                                     st2, g2, bt2, 1.0f / (float)C1n,
                                     st3, g3, bt3, 1.0f / (float)C2n,
                                     scsh1, scsh2, scsh3);
    k_final<<<cdiv(N, T), T, 0, stream>>>(acc1, scsh1, acc2, scsh2, cl1,
                                          acc3, scsh3, cl2,
                                          x, Wm, bm, (float*)d_out, N);
}

// Round 8
// 760.847 us; speedup vs baseline: 2.8970x; 2.8970x over previous
//
#include <hip/hip_runtime.h>
#include <algorithm>

#define FIN 24
#define NHID 64
#define NMIX 216
#define NOUT 6
#define BN_EPS 1e-5f

// ---------- CSR build ----------
__global__ void k_hist(const int* __restrict__ ei, int E, int* deg) {
    int e = blockIdx.x * blockDim.x + threadIdx.x;
    if (e < E) atomicAdd(&deg[ei[E + e]], 1);
}

__global__ void k_dis(const int* __restrict__ deg, float* dis, int n) {
    int i = blockIdx.x * blockDim.x + threadIdx.x;
    if (i < n) { int v = deg[i]; dis[i] = v > 0 ? rsqrtf((float)v) : 0.f; }
}

// block-local exclusive scan over deg (n+1 elements, deg[i>=n]:=0); totals -> bsum
__global__ void k_scan_local(const int* __restrict__ deg, int n, int* rowptr, int* bsum) {
    __shared__ int s[256];
    int i = blockIdx.x * 256 + threadIdx.x;
    int v = (i < n) ? deg[i] : 0;
    s[threadIdx.x] = v;
    __syncthreads();
#pragma unroll
    for (int off = 1; off < 256; off <<= 1) {
        int x = (threadIdx.x >= off) ? s[threadIdx.x - off] : 0;
        __syncthreads();
        s[threadIdx.x] += x;
        __syncthreads();
    }
    if (i <= n) rowptr[i] = s[threadIdx.x] - v;  // exclusive
    if (threadIdx.x == 255) bsum[blockIdx.x] = s[255];
}

__global__ void k_scan_bsum(int* bsum, int nb) {
    __shared__ int s[256];
    int carry = 0;
    for (int base = 0; base < nb; base += 256) {
        int i = base + threadIdx.x;
        int v = (i < nb) ? bsum[i] : 0;
        s[threadIdx.x] = v;
        __syncthreads();
#pragma unroll
        for (int off = 1; off < 256; off <<= 1) {
            int x = (threadIdx.x >= off) ? s[threadIdx.x - off] : 0;
            __syncthreads();
            s[threadIdx.x] += x;
            __syncthreads();
        }
        if (i < nb) bsum[i] = s[threadIdx.x] - v + carry;
        carry += s[255];
        __syncthreads();
    }
}

__global__ void k_scan_add(int* rowptr, const int* __restrict__ bsum, int n) {
    int i = blockIdx.x * 256 + threadIdx.x;
    if (i <= n) rowptr[i] += bsum[blockIdx.x];
}

__global__ void k_fill(const int* __restrict__ ei, int E, const float* __restrict__ dis,
                       const int* __restrict__ rowptr, int* fill,
                       int* __restrict__ col, float* __restrict__ val) {
    int e = blockIdx.x * blockDim.x + threadIdx.x;
    if (e >= E) return;
    int s = ei[e], d = ei[E + e];
    int slot = rowptr[d] + atomicAdd(&fill[d], 1);
    col[slot] = s;
    val[slot] = -dis[s] * dis[d];
}

// ---------- gather prop, thread per dst node (full 24-float row) ----------
__global__ void k_propg(const int* __restrict__ rowptr, const int* __restrict__ col,
                        const float* __restrict__ val, float scale,
                        const float* __restrict__ h, const float* __restrict__ prev,
                        float* __restrict__ out, int n) {
    int t = blockIdx.x * blockDim.x + threadIdx.x;
    if (t >= n) return;
    int beg = rowptr[t], end = rowptr[t + 1];
    float4 a[6];
#pragma unroll
    for (int q = 0; q < 6; ++q) a[q] = make_float4(0.f, 0.f, 0.f, 0.f);
    for (int e = beg; e < end; ++e) {
        float w = val[e];
        const float4* hp = reinterpret_cast<const float4*>(h + (size_t)col[e] * FIN);
#pragma unroll
        for (int q = 0; q < 6; ++q) {
            float4 hv = hp[q];
            a[q].x = fmaf(w, hv.x, a[q].x);
            a[q].y = fmaf(w, hv.y, a[q].y);
            a[q].z = fmaf(w, hv.z, a[q].z);
            a[q].w = fmaf(w, hv.w, a[q].w);
        }
    }
    float4* op = reinterpret_cast<float4*>(out + (size_t)t * FIN);
    if (prev) {
        const float4* pp = reinterpret_cast<const float4*>(prev + (size_t)t * FIN);
#pragma unroll
        for (int q = 0; q < 6; ++q) {
            float4 pv = pp[q];
            op[q] = make_float4(fmaf(scale, a[q].x, -pv.x), fmaf(scale, a[q].y, -pv.y),
                                fmaf(scale, a[q].z, -pv.z), fmaf(scale, a[q].w, -pv.w));
        }
    } else {
#pragma unroll
        for (int q = 0; q < 6; ++q)
            op[q] = make_float4(scale * a[q].x, scale * a[q].y, scale * a[q].z, scale * a[q].w);
    }
}

// acc[node][j] (=|+=) S1@Wa + S2@Wb (+bias); lane=j, wave-uniform node.
// Wave-local LDS staging: each wave stages its 16 nodes' S1/S2 rows with
// 3 coalesced float4 loads + 3 ds_writes per lane (192 float4 slots/wave),
// then computes from LDS broadcast reads. No __syncthreads (wave-private
// LDS region). One block per 64-node tile.
__global__ void k_gemv2(const float* __restrict__ S1, const float* __restrict__ S2,
                        const float* __restrict__ Wa, const float* __restrict__ Wb,
                        const float* __restrict__ bias, float* __restrict__ acc,
                        float* __restrict__ stats, int n) {
    __shared__ float sb[4][2][16 * FIN];  // [wave][S1/S2][16 nodes * 24 floats] = 12 KB
    int j = threadIdx.x & 63;
    int w = threadIdx.x >> 6;
    float wa[FIN], wb[FIN];
#pragma unroll
    for (int f = 0; f < FIN; ++f) wa[f] = Wa[f * NHID + j];
#pragma unroll
    for (int f = 0; f < FIN; ++f) wb[f] = Wb[f * NHID + j];
    int nbase = blockIdx.x * 64 + w * 16;
    // ---- stage: 192 float4 per wave (96 per S-half = 16 nodes * 6); 3 per lane ----
#pragma unroll
    for (int k = 0; k < 3; ++k) {
        int i = k * 64 + j;            // 0..191
        int half = i / 96;             // 0: S1, 1: S2
        int j4 = i - half * 96;        // 0..95
        int nd = j4 / 6, q = j4 - nd * 6;   // nd: 0..15, q: 0..5
        int node = nbase + nd;
        const float* src = (half ? S2 : S1) + (size_t)node * FIN + q * 4;
        float4 v = (node < n) ? *reinterpret_cast<const float4*>(src)
                              : make_float4(0.f, 0.f, 0.f, 0.f);
        *reinterpret_cast<float4*>(&sb[w][half][j4 * 4]) = v;
    }
    // ---- compute 16 nodes ----
    float sum = 0.f, sq = 0.f;
#pragma unroll 2
    for (int nd = 0; nd < 16; ++nd) {
        int node = nbase + nd;
        bool ok = (node < n);
        int nodec = ok ? node : 0;
        float base = bias ? bias[j] : acc[(size_t)nodec * NHID + j];
        const float4* r1 = reinterpret_cast<const float4*>(&sb[w][0][nd * FIN]);
        const float4* r2 = reinterpret_cast<const float4*>(&sb[w][1][nd * FIN]);
        float a = 0.f, p = 0.f;
#pragma unroll
        for (int t = 0; t < 6; ++t) {
            float4 v = r1[t];
            a = fmaf(v.x, wa[t * 4 + 0], a);
            p = fmaf(v.y, wa[t * 4 + 1], p);
            a = fmaf(v.z, wa[t * 4 + 2], a);
            p = fmaf(v.w, wa[t * 4 + 3], p);
        }
#pragma unroll
        for (int t = 0; t < 6; ++t) {
            float4 v = r2[t];
            a = fmaf(v.x, wb[t * 4 + 0], a);
            p = fmaf(v.y, wb[t * 4 + 1], p);
            a = fmaf(v.z, wb[t * 4 + 2], a);
            p = fmaf(v.w, wb[t * 4 + 3], p);
        }
        float r = base + a + p;
        if (ok) {
            acc[(size_t)node * NHID + j] = r;
            sum += r; sq = fmaf(r, r, sq);
        }
    }
    if (stats) {
        __shared__ float rs[256], rq[256];
        rs[threadIdx.x] = sum; rq[threadIdx.x] = sq;
        __syncthreads();
        if (threadIdx.x < 64) {
            float s = rs[threadIdx.x] + rs[threadIdx.x + 64] + rs[threadIdx.x + 128] + rs[threadIdx.x + 192];
            float q = rq[threadIdx.x] + rq[threadIdx.x + 64] + rq[threadIdx.x + 128] + rq[threadIdx.x + 192];
            atomicAdd(&stats[threadIdx.x], s);
            atomicAdd(&stats[NHID + threadIdx.x], q);
        }
    }
}

// BN coefficients for all 3 branches: scX[0:64]=scale, scX[64:128]=shift
__global__ void k_bnprep3(const float* __restrict__ st1, const float* __restrict__ g1,
                          const float* __restrict__ bt1, float inv1,
                          const float* __restrict__ st2, const float* __restrict__ g2,
                          const float* __restrict__ bt2, float inv2,
                          const float* __restrict__ st3, const float* __restrict__ g3,
                          const float* __restrict__ bt3, float inv3,
                          float* __restrict__ s1, float* __restrict__ s2,
                          float* __restrict__ s3) {
    int b = threadIdx.x >> 6, i = threadIdx.x & 63;
    const float* st = (b == 0) ? st1 : (b == 1) ? st2 : st3;
    const float* g  = (b == 0) ? g1  : (b == 1) ? g2  : g3;
    const float* bt = (b == 0) ? bt1 : (b == 1) ? bt2 : bt3;
    float inv       = (b == 0) ? inv1 : (b == 1) ? inv2 : inv3;
    float* so       = (b == 0) ? s1  : (b == 1) ? s2  : s3;
    float m = st[i] * inv;
    float v = st[NHID + i] * inv - m * m;
    float sc = g[i] * rsqrtf(v + BN_EPS);
    so[i] = sc;
    so[NHID + i] = fmaf(-m, sc, bt[i]);
}

// segment-mean scatter
__global__ void k_scatter(const float* __restrict__ x, const int* __restrict__ cl,
                          int n, float* xp, float* cnt) {
    int idx = blockIdx.x * blockDim.x + threadIdx.x;
    if (idx >= n * FIN) return;
    int node = idx / FIN, f = idx - node * FIN;
    int c = cl[node];
    atomicAdd(&xp[c * FIN + f], x[idx]);
    if (f == 0) atomicAdd(&cnt[c], 1.f);
}

__global__ void k_divcnt(float* xp, const float* __restrict__ cnt, int c) {
    int idx = blockIdx.x * blockDim.x + threadIdx.x;
    if (idx >= c * FIN) return;
    xp[idx] = xp[idx] / fmaxf(cnt[idx / FIN], 1.f);
}

// fused mix: thread per node; BN+ReLU for all three branches via precomputed
// scale/shift (uniform scalar loads); Wm/bm scalar-indexed.
__global__ void k_final(const float* __restrict__ acc1, const float* __restrict__ sc1,
                        const float* __restrict__ h2, const float* __restrict__ sc2,
                        const int* __restrict__ cl1,
                        const float* __restrict__ h3, const float* __restrict__ sc3,
                        const int* __restrict__ cl2,
                        const float* __restrict__ x, const float* __restrict__ Wm,
                        const float* __restrict__ bm, float* __restrict__ out, int n) {
    int t = blockIdx.x * blockDim.x + threadIdx.x;
    if (t >= n) return;
    float o[NOUT];
#pragma unroll
    for (int j = 0; j < NOUT; ++j) o[j] = bm[j];
    {
        const float4* r4 = reinterpret_cast<const float4*>(acc1 + (size_t)t * NHID);
#pragma unroll
        for (int i4 = 0; i4 < NHID / 4; ++i4) {
            float4 v = r4[i4];
            float hv[4] = {v.x, v.y, v.z, v.w};
#pragma unroll
            for (int c = 0; c < 4; ++c) {
                int i = i4 * 4 + c;
                float h = fmaxf(fmaf(hv[c], sc1[i], sc1[NHID + i]), 0.f);
#pragma unroll
                for (int j = 0; j < NOUT; ++j) o[j] = fmaf(h, Wm[i * NOUT + j], o[j]);
            }
        }
    }
    {
        const float4* r4 = reinterpret_cast<const float4*>(h2 + (size_t)cl1[t] * NHID);
#pragma unroll
        for (int i4 = 0; i4 < NHID / 4; ++i4) {
            float4 v = r4[i4];
            float hv[4] = {v.x, v.y, v.z, v.w};
#pragma unroll
            for (int c = 0; c < 4; ++c) {
                int hid = i4 * 4 + c;
                float h = fmaxf(fmaf(hv[c], sc2[hid], sc2[NHID + hid]), 0.f);
#pragma unroll
                for (int j = 0; j < NOUT; ++j) o[j] = fmaf(h, Wm[(NHID + hid) * NOUT + j], o[j]);
            }
        }
    }
    {
        const float4* r4 = reinterpret_cast<const float4*>(h3 + (size_t)cl2[t] * NHID);
#pragma unroll
        for (int i4 = 0; i4 < NHID / 4; ++i4) {
            float4 v = r4[i4];
            float hv[4] = {v.x, v.y, v.z, v.w};
#pragma unroll
            for (int c = 0; c < 4; ++c) {
                int hid = i4 * 4 + c;
                float h = fmaxf(fmaf(hv[c], sc3[hid], sc3[NHID + hid]), 0.f);
#pragma unroll
                for (int j = 0; j < NOUT; ++j) o[j] = fmaf(h, Wm[(2 * NHID + hid) * NOUT + j], o[j]);
            }
        }
    }
    {
        const float4* r4 = reinterpret_cast<const float4*>(x + (size_t)t * FIN);
#pragma unroll
        for (int i4 = 0; i4 < FIN / 4; ++i4) {
            float4 v = r4[i4];
            float hv[4] = {v.x, v.y, v.z, v.w};
#pragma unroll
            for (int c = 0; c < 4; ++c) {
                int i = 3 * NHID + i4 * 4 + c;
#pragma unroll
                for (int j = 0; j < NOUT; ++j) o[j] = fmaf(hv[c], Wm[i * NOUT + j], o[j]);
            }
        }
    }
    float* op = out + (size_t)t * NOUT;
#pragma unroll
    for (int j = 0; j < NOUT; ++j) op[j] = o[j];
}

extern "C" void kernel_launch(void* const* d_in, const int* in_sizes, int n_in,
                              void* d_out, int out_size, void* d_ws, size_t ws_size,
                              hipStream_t stream) {
    const int N = 200000, E = 800000;
    const int C1n = 20000, E1 = 80000;
    const int C2n = 2000, E2 = 8000;

    const float* x  = (const float*)d_in[0];
    const int* ei   = (const int*)d_in[1];
    const int* cl1  = (const int*)d_in[2];
    const int* cl2  = (const int*)d_in[3];
    const int* eic1 = (const int*)d_in[4];
    const int* eic2 = (const int*)d_in[5];
    const float* W1 = (const float*)d_in[6];  const float* b1 = (const float*)d_in[7];
    const float* g1 = (const float*)d_in[8];  const float* bt1 = (const float*)d_in[9];
    const float* W2 = (const float*)d_in[10]; const float* b2 = (const float*)d_in[11];
    const float* g2 = (const float*)d_in[12]; const float* bt2 = (const float*)d_in[13];
    const float* W3 = (const float*)d_in[14]; const float* b3 = (const float*)d_in[15];
    const float* g3 = (const float*)d_in[16]; const float* bt3 = (const float*)d_in[17];
    const float* Wm = (const float*)d_in[18]; const float* bm = (const float*)d_in[19];

    char* wb = (char*)d_ws;
    size_t off = 0;
    auto alloc = [&](size_t nwords) {
        void* p = wb + off; off += ((nwords + 3) & ~(size_t)3) * 4; return p;
    };
    // --- zero-region ---
    int* degi1 = (int*)alloc(N);   int* fill1 = (int*)alloc(N);
    int* degi2 = (int*)alloc(C1n); int* fill2 = (int*)alloc(C1n);
    int* degi3 = (int*)alloc(C2n); int* fill3 = (int*)alloc(C2n);
    float* st1 = (float*)alloc(128); float* st2 = (float*)alloc(128); float* st3 = (float*)alloc(128);
    float* xp1 = (float*)alloc((size_t)C1n * FIN); float* cnt1 = (float*)alloc(C1n);
    float* xp2 = (float*)alloc((size_t)C2n * FIN); float* cnt2 = (float*)alloc(C2n);
    size_t zero_bytes = off;
    // --- fully-overwritten region ---
    int* rp1 = (int*)alloc(N + 1);   int* col1 = (int*)alloc(E);  float* val1 = (float*)alloc(E);
    int* rp2 = (int*)alloc(C1n + 1); int* col2 = (int*)alloc(E1); float* val2 = (float*)alloc(E1);
    int* rp3 = (int*)alloc(C2n + 1); int* col3 = (int*)alloc(E2); float* val3 = (float*)alloc(E2);
    float* dis1 = (float*)alloc(N); float* dis2 = (float*)alloc(C1n); float* dis3 = (float*)alloc(C2n);
    int* bsum = (int*)alloc(1024);
    float* scsh1 = (float*)alloc(128); float* scsh2 = (float*)alloc(128); float* scsh3 = (float*)alloc(128);
    float* B1_0 = (float*)alloc((size_t)N * FIN);   float* B1_1 = (float*)alloc((size_t)N * FIN);
    float* B2_0 = (float*)alloc((size_t)C1n * FIN); float* B2_1 = (float*)alloc((size_t)C1n * FIN);
    float* B3_0 = (float*)alloc((size_t)C2n * FIN); float* B3_1 = (float*)alloc((size_t)C2n * FIN);
    float* acc1 = (float*)alloc((size_t)N * NHID);
    float* acc2 = (float*)alloc((size_t)C1n * NHID);
    float* acc3 = (float*)alloc((size_t)C2n * NHID);
    if (off > ws_size) return;  // fail visibly if ws too small

    hipMemsetAsync(d_ws, 0, zero_bytes, stream);

    const int T = 256;
    auto cdiv = [](int a, int b) { return (a + b - 1) / b; };

    auto branch = [&](const float* xin, int n, const int* e, int Ecnt,
                      const float* W, const float* bb, int* degi, int* fill, float* dis,
                      int* rp, int* col, float* val,
                      float* B0, float* Bb1, float* acc, float* st) {
        int ge = cdiv(Ecnt, T), gn = cdiv(n, T);
        int nb = cdiv(n + 1, 256);
        int gg = cdiv(n, 64);  // one 64-node tile per block
        const int WSZ = FIN * NHID;
        // CSR build
        k_hist<<<ge, T, 0, stream>>>(e, Ecnt, degi);
        k_dis<<<gn, T, 0, stream>>>(degi, dis, n);
        k_scan_local<<<nb, 256, 0, stream>>>(degi, n, rp, bsum);
        k_scan_bsum<<<1, 256, 0, stream>>>(bsum, nb);
        k_scan_add<<<nb, 256, 0, stream>>>(rp, bsum, n);
        k_fill<<<ge, T, 0, stream>>>(e, Ecnt, dis, rp, fill, col, val);
        // Tx1 = P(x) -> B0
        k_propg<<<gn, T, 0, stream>>>(rp, col, val, 1.0f, xin, nullptr, B0, n);
        // acc = b + x@W0 + Tx1@W1
        k_gemv2<<<gg, T, 0, stream>>>(xin, B0, W, W + WSZ, bb, acc, nullptr, n);
        // Tx2 = 2P(Tx1) - x -> Bb1
        k_propg<<<gn, T, 0, stream>>>(rp, col, val, 2.0f, B0, xin, Bb1, n);
        // Tx3 = 2P(Tx2) - Tx1 -> B0 (in place over prev)
        k_propg<<<gn, T, 0, stream>>>(rp, col, val, 2.0f, Bb1, B0, B0, n);
        // acc += Tx2@W2 + Tx3@W3
        k_gemv2<<<gg, T, 0, stream>>>(Bb1, B0, W + 2 * WSZ, W + 3 * WSZ, nullptr, acc, nullptr, n);
        // Tx4 = 2P(Tx3) - Tx2 -> Bb1
        k_propg<<<gn, T, 0, stream>>>(rp, col, val, 2.0f, B0, Bb1, Bb1, n);
        // Tx5 = 2P(Tx4) - Tx3 -> B0
        k_propg<<<gn, T, 0, stream>>>(rp, col, val, 2.0f, Bb1, B0, B0, n);
        // acc += Tx4@W4 + Tx5@W5 (+BN stats)
        k_gemv2<<<gg, T, 0, stream>>>(Bb1, B0, W + 4 * WSZ, W + 5 * WSZ, nullptr, acc, st, n);
    };

    // branch 1: full graph
    branch(x, N, ei, E, W1, b1, degi1, fill1, dis1, rp1, col1, val1, B1_0, B1_1, acc1, st1);
    // branch 2
    k_scatter<<<cdiv(N * FIN, T), T, 0, stream>>>(x, cl1, N, xp1, cnt1);
    k_divcnt<<<cdiv(C1n * FIN, T), T, 0, stream>>>(xp1, cnt1, C1n);
    branch(xp1, C1n, eic1, E1, W2, b2, degi2, fill2, dis2, rp2, col2, val2, B2_0, B2_1, acc2, st2);
    // branch 3
    k_scatter<<<cdiv(N * FIN, T), T, 0, stream>>>(x, cl2, N, xp2, cnt2);
    k_divcnt<<<cdiv(C2n * FIN, T), T, 0, stream>>>(xp2, cnt2, C2n);
    branch(xp2, C2n, eic2, E2, W3, b3, degi3, fill3, dis3, rp3, col3, val3, B3_0, B3_1, acc3, st3);
    // BN coefficients for all three branches, then fused final mix
    k_bnprep3<<<1, 192, 0, stream>>>(st1, g1, bt1, 1.0f / (float)N,
                                     st2, g2, bt2, 1.0f / (float)C1n,
                                     st3, g3, bt3, 1.0f / (float)C2n,
                                     scsh1, scsh2, scsh3);
    k_final<<<cdiv(N, T), T, 0, stream>>>(acc1, scsh1, acc2, scsh2, cl1,
                                          acc3, scsh3, cl2,
                                          x, Wm, bm, (float*)d_out, N);
}

// Round 9
// 679.629 us; speedup vs baseline: 3.2431x; 1.1195x over previous
//
#include <hip/hip_runtime.h>
#include <algorithm>

#define FIN 24
#define NHID 64
#define NMIX 216
#define NOUT 6
#define BN_EPS 1e-5f

// ---------- CSR build ----------
__global__ void k_hist(const int* __restrict__ ei, int E, int* deg) {
    int e = blockIdx.x * blockDim.x + threadIdx.x;
    if (e < E) atomicAdd(&deg[ei[E + e]], 1);
}

__global__ void k_dis(const int* __restrict__ deg, float* dis, int n) {
    int i = blockIdx.x * blockDim.x + threadIdx.x;
    if (i < n) { int v = deg[i]; dis[i] = v > 0 ? rsqrtf((float)v) : 0.f; }
}

// block-local exclusive scan over deg (n+1 elements, deg[i>=n]:=0); totals -> bsum
__global__ void k_scan_local(const int* __restrict__ deg, int n, int* rowptr, int* bsum) {
    __shared__ int s[256];
    int i = blockIdx.x * 256 + threadIdx.x;
    int v = (i < n) ? deg[i] : 0;
    s[threadIdx.x] = v;
    __syncthreads();
#pragma unroll
    for (int off = 1; off < 256; off <<= 1) {
        int x = (threadIdx.x >= off) ? s[threadIdx.x - off] : 0;
        __syncthreads();
        s[threadIdx.x] += x;
        __syncthreads();
    }
    if (i <= n) rowptr[i] = s[threadIdx.x] - v;  // exclusive
    if (threadIdx.x == 255) bsum[blockIdx.x] = s[255];
}

__global__ void k_scan_bsum(int* bsum, int nb) {
    __shared__ int s[256];
    int carry = 0;
    for (int base = 0; base < nb; base += 256) {
        int i = base + threadIdx.x;
        int v = (i < nb) ? bsum[i] : 0;
        s[threadIdx.x] = v;
        __syncthreads();
#pragma unroll
        for (int off = 1; off < 256; off <<= 1) {
            int x = (threadIdx.x >= off) ? s[threadIdx.x - off] : 0;
            __syncthreads();
            s[threadIdx.x] += x;
            __syncthreads();
        }
        if (i < nb) bsum[i] = s[threadIdx.x] - v + carry;
        carry += s[255];
        __syncthreads();
    }
}

__global__ void k_scan_add(int* rowptr, const int* __restrict__ bsum, int n) {
    int i = blockIdx.x * 256 + threadIdx.x;
    if (i <= n) rowptr[i] += bsum[blockIdx.x];
}

// fill CSR with packed (col, val) per edge
__global__ void k_fill(const int* __restrict__ ei, int E, const float* __restrict__ dis,
                       const int* __restrict__ rowptr, int* fill, int2* __restrict__ cv) {
    int e = blockIdx.x * blockDim.x + threadIdx.x;
    if (e >= E) return;
    int s = ei[e], d = ei[E + e];
    int slot = rowptr[d] + atomicAdd(&fill[d], 1);
    cv[slot] = make_int2(s, __float_as_int(-dis[s] * dis[d]));
}

// ---------- gather prop, thread per (dst node, float4 chunk) ----------
// out[d][q] = scale * sum_e val[e]*h[col[e]][q]  (- prev[d][q]); prev may alias out.
// Edge loop unrolled x2 with dual accumulators (2 gathers in flight).
__global__ void k_propg(const int* __restrict__ rowptr, const int2* __restrict__ cv,
                        float scale, const float* __restrict__ h,
                        const float* __restrict__ prev, float* __restrict__ out, int n) {
    int idx = blockIdx.x * blockDim.x + threadIdx.x;
    if (idx >= n * 6) return;
    int d = idx / 6, q = idx - d * 6;
    int beg = rowptr[d], end = rowptr[d + 1];
    const float4* h4 = reinterpret_cast<const float4*>(h);
    float ax = 0.f, ay = 0.f, az = 0.f, aw = 0.f;
    float bx = 0.f, by = 0.f, bz = 0.f, bw = 0.f;
    int e = beg;
    for (; e + 2 <= end; e += 2) {
        int2 c0 = cv[e], c1 = cv[e + 1];
        float w0 = __int_as_float(c0.y), w1 = __int_as_float(c1.y);
        float4 h0 = h4[(size_t)c0.x * 6 + q];
        float4 h1 = h4[(size_t)c1.x * 6 + q];
        ax = fmaf(w0, h0.x, ax); ay = fmaf(w0, h0.y, ay);
        az = fmaf(w0, h0.z, az); aw = fmaf(w0, h0.w, aw);
        bx = fmaf(w1, h1.x, bx); by = fmaf(w1, h1.y, by);
        bz = fmaf(w1, h1.z, bz); bw = fmaf(w1, h1.w, bw);
    }
    if (e < end) {
        int2 c0 = cv[e];
        float w0 = __int_as_float(c0.y);
        float4 h0 = h4[(size_t)c0.x * 6 + q];
        ax = fmaf(w0, h0.x, ax); ay = fmaf(w0, h0.y, ay);
        az = fmaf(w0, h0.z, az); aw = fmaf(w0, h0.w, aw);
    }
    ax += bx; ay += by; az += bz; aw += bw;
    float4 r;
    if (prev) {
        float4 pv = reinterpret_cast<const float4*>(prev)[idx];
        r = make_float4(fmaf(scale, ax, -pv.x), fmaf(scale, ay, -pv.y),
                        fmaf(scale, az, -pv.z), fmaf(scale, aw, -pv.w));
    } else {
        r = make_float4(scale * ax, scale * ay, scale * az, scale * aw);
    }
    reinterpret_cast<float4*>(out)[idx] = r;
}

// acc[node][j] (=|+=) S1@Wa + S2@Wb (+bias); lane=j, wave-uniform node.
// Wave-local LDS staging (3 coalesced float4 loads + 3 ds_writes per lane);
// all 16 acc bases prefetched into registers (MLP 16) before the fully
// unrolled compute loop. No __syncthreads (wave-private LDS region).
__global__ void k_gemv2(const float* __restrict__ S1, const float* __restrict__ S2,
                        const float* __restrict__ Wa, const float* __restrict__ Wb,
                        const float* __restrict__ bias, float* __restrict__ acc,
                        float* __restrict__ stats, int n) {
    __shared__ float sb[4][2][16 * FIN];  // [wave][S1/S2][16 nodes * 24 floats] = 12 KB
    int j = threadIdx.x & 63;
    int w = threadIdx.x >> 6;
    int nbase = blockIdx.x * 64 + w * 16;
    // ---- prefetch 16 acc bases (or bias) ----
    float bases[16];
    if (bias) {
        float bb = bias[j];
#pragma unroll
        for (int nd = 0; nd < 16; ++nd) bases[nd] = bb;
    } else {
#pragma unroll
        for (int nd = 0; nd < 16; ++nd) {
            int node = nbase + nd;
            bases[nd] = (node < n) ? acc[(size_t)node * NHID + j] : 0.f;
        }
    }
    float wa[FIN], wb[FIN];
#pragma unroll
    for (int f = 0; f < FIN; ++f) wa[f] = Wa[f * NHID + j];
#pragma unroll
    for (int f = 0; f < FIN; ++f) wb[f] = Wb[f * NHID + j];
    // ---- stage: 192 float4 per wave (96 per S-half = 16 nodes * 6); 3 per lane ----
#pragma unroll
    for (int k = 0; k < 3; ++k) {
        int i = k * 64 + j;            // 0..191
        int half = i / 96;             // 0: S1, 1: S2
        int j4 = i - half * 96;        // 0..95
        int nd = j4 / 6, q = j4 - nd * 6;   // nd: 0..15, q: 0..5
        int node = nbase + nd;
        const float* src = (half ? S2 : S1) + (size_t)node * FIN + q * 4;
        float4 v = (node < n) ? *reinterpret_cast<const float4*>(src)
                              : make_float4(0.f, 0.f, 0.f, 0.f);
        *reinterpret_cast<float4*>(&sb[w][half][j4 * 4]) = v;
    }
    // ---- compute 16 nodes (fully unrolled; bases statically indexed) ----
    float sum = 0.f, sq = 0.f;
#pragma unroll
    for (int nd = 0; nd < 16; ++nd) {
        int node = nbase + nd;
        const float4* r1 = reinterpret_cast<const float4*>(&sb[w][0][nd * FIN]);
        const float4* r2 = reinterpret_cast<const float4*>(&sb[w][1][nd * FIN]);
        float a = 0.f, p = 0.f;
#pragma unroll
        for (int t = 0; t < 6; ++t) {
            float4 v = r1[t];
            a = fmaf(v.x, wa[t * 4 + 0], a);
            p = fmaf(v.y, wa[t * 4 + 1], p);
            a = fmaf(v.z, wa[t * 4 + 2], a);
            p = fmaf(v.w, wa[t * 4 + 3], p);
        }
#pragma unroll
        for (int t = 0; t < 6; ++t) {
            float4 v = r2[t];
            a = fmaf(v.x, wb[t * 4 + 0], a);
            p = fmaf(v.y, wb[t * 4 + 1], p);
            a = fmaf(v.z, wb[t * 4 + 2], a);
            p = fmaf(v.w, wb[t * 4 + 3], p);
        }
        float r = bases[nd] + a + p;
        if (node < n) {
            acc[(size_t)node * NHID + j] = r;
            sum += r; sq = fmaf(r, r, sq);
        }
    }
    if (stats) {
        __shared__ float rs[256], rq[256];
        rs[threadIdx.x] = sum; rq[threadIdx.x] = sq;
        __syncthreads();
        if (threadIdx.x < 64) {
            float s = rs[threadIdx.x] + rs[threadIdx.x + 64] + rs[threadIdx.x + 128] + rs[threadIdx.x + 192];
            float q = rq[threadIdx.x] + rq[threadIdx.x + 64] + rq[threadIdx.x + 128] + rq[threadIdx.x + 192];
            atomicAdd(&stats[threadIdx.x], s);
            atomicAdd(&stats[NHID + threadIdx.x], q);
        }
    }
}

// BN coefficients for all 3 branches: scX[0:64]=scale, scX[64:128]=shift
__global__ void k_bnprep3(const float* __restrict__ st1, const float* __restrict__ g1,
                          const float* __restrict__ bt1, float inv1,
                          const float* __restrict__ st2, const float* __restrict__ g2,
                          const float* __restrict__ bt2, float inv2,
                          const float* __restrict__ st3, const float* __restrict__ g3,
                          const float* __restrict__ bt3, float inv3,
                          float* __restrict__ s1, float* __restrict__ s2,
                          float* __restrict__ s3) {
    int b = threadIdx.x >> 6, i = threadIdx.x & 63;
    const float* st = (b == 0) ? st1 : (b == 1) ? st2 : st3;
    const float* g  = (b == 0) ? g1  : (b == 1) ? g2  : g3;
    const float* bt = (b == 0) ? bt1 : (b == 1) ? bt2 : bt3;
    float inv       = (b == 0) ? inv1 : (b == 1) ? inv2 : inv3;
    float* so       = (b == 0) ? s1  : (b == 1) ? s2  : s3;
    float m = st[i] * inv;
    float v = st[NHID + i] * inv - m * m;
    float sc = g[i] * rsqrtf(v + BN_EPS);
    so[i] = sc;
    so[NHID + i] = fmaf(-m, sc, bt[i]);
}

// segment-mean scatter
__global__ void k_scatter(const float* __restrict__ x, const int* __restrict__ cl,
                          int n, float* xp, float* cnt) {
    int idx = blockIdx.x * blockDim.x + threadIdx.x;
    if (idx >= n * FIN) return;
    int node = idx / FIN, f = idx - node * FIN;
    int c = cl[node];
    atomicAdd(&xp[c * FIN + f], x[idx]);
    if (f == 0) atomicAdd(&cnt[c], 1.f);
}

__global__ void k_divcnt(float* xp, const float* __restrict__ cnt, int c) {
    int idx = blockIdx.x * blockDim.x + threadIdx.x;
    if (idx >= c * FIN) return;
    xp[idx] = xp[idx] / fmaxf(cnt[idx / FIN], 1.f);
}

// fused mix: thread per node; BN+ReLU for all three branches via precomputed
// scale/shift (uniform scalar loads); Wm/bm scalar-indexed.
__global__ void k_final(const float* __restrict__ acc1, const float* __restrict__ sc1,
                        const float* __restrict__ h2, const float* __restrict__ sc2,
                        const int* __restrict__ cl1,
                        const float* __restrict__ h3, const float* __restrict__ sc3,
                        const int* __restrict__ cl2,
                        const float* __restrict__ x, const float* __restrict__ Wm,
                        const float* __restrict__ bm, float* __restrict__ out, int n) {
    int t = blockIdx.x * blockDim.x + threadIdx.x;
    if (t >= n) return;
    float o[NOUT];
#pragma unroll
    for (int j = 0; j < NOUT; ++j) o[j] = bm[j];
    {
        const float4* r4 = reinterpret_cast<const float4*>(acc1 + (size_t)t * NHID);
#pragma unroll
        for (int i4 = 0; i4 < NHID / 4; ++i4) {
            float4 v = r4[i4];
            float hv[4] = {v.x, v.y, v.z, v.w};
#pragma unroll
            for (int c = 0; c < 4; ++c) {
                int i = i4 * 4 + c;
                float h = fmaxf(fmaf(hv[c], sc1[i], sc1[NHID + i]), 0.f);
#pragma unroll
                for (int j = 0; j < NOUT; ++j) o[j] = fmaf(h, Wm[i * NOUT + j], o[j]);
            }
        }
    }
    {
        const float4* r4 = reinterpret_cast<const float4*>(h2 + (size_t)cl1[t] * NHID);
#pragma unroll
        for (int i4 = 0; i4 < NHID / 4; ++i4) {
            float4 v = r4[i4];
            float hv[4] = {v.x, v.y, v.z, v.w};
#pragma unroll
            for (int c = 0; c < 4; ++c) {
                int hid = i4 * 4 + c;
                float h = fmaxf(fmaf(hv[c], sc2[hid], sc2[NHID + hid]), 0.f);
#pragma unroll
                for (int j = 0; j < NOUT; ++j) o[j] = fmaf(h, Wm[(NHID + hid) * NOUT + j], o[j]);
            }
        }
    }
    {
        const float4* r4 = reinterpret_cast<const float4*>(h3 + (size_t)cl2[t] * NHID);
#pragma unroll
        for (int i4 = 0; i4 < NHID / 4; ++i4) {
            float4 v = r4[i4];
            float hv[4] = {v.x, v.y, v.z, v.w};
#pragma unroll
            for (int c = 0; c < 4; ++c) {
                int hid = i4 * 4 + c;
                float h = fmaxf(fmaf(hv[c], sc3[hid], sc3[NHID + hid]), 0.f);
#pragma unroll
                for (int j = 0; j < NOUT; ++j) o[j] = fmaf(h, Wm[(2 * NHID + hid) * NOUT + j], o[j]);
            }
        }
    }
    {
        const float4* r4 = reinterpret_cast<const float4*>(x + (size_t)t * FIN);
#pragma unroll
        for (int i4 = 0; i4 < FIN / 4; ++i4) {
            float4 v = r4[i4];
            float hv[4] = {v.x, v.y, v.z, v.w};
#pragma unroll
            for (int c = 0; c < 4; ++c) {
                int i = 3 * NHID + i4 * 4 + c;
#pragma unroll
                for (int j = 0; j < NOUT; ++j) o[j] = fmaf(hv[c], Wm[i * NOUT + j], o[j]);
            }
        }
    }
    float* op = out + (size_t)t * NOUT;
#pragma unroll
    for (int j = 0; j < NOUT; ++j) op[j] = o[j];
}

extern "C" void kernel_launch(void* const* d_in, const int* in_sizes, int n_in,
                              void* d_out, int out_size, void* d_ws, size_t ws_size,
                              hipStream_t stream) {
    const int N = 200000, E = 800000;
    const int C1n = 20000, E1 = 80000;
    const int C2n = 2000, E2 = 8000;

    const float* x  = (const float*)d_in[0];
    const int* ei   = (const int*)d_in[1];
    const int* cl1  = (const int*)d_in[2];
    const int* cl2  = (const int*)d_in[3];
    const int* eic1 = (const int*)d_in[4];
    const int* eic2 = (const int*)d_in[5];
    const float* W1 = (const float*)d_in[6];  const float* b1 = (const float*)d_in[7];
    const float* g1 = (const float*)d_in[8];  const float* bt1 = (const float*)d_in[9];
    const float* W2 = (const float*)d_in[10]; const float* b2 = (const float*)d_in[11];
    const float* g2 = (const float*)d_in[12]; const float* bt2 = (const float*)d_in[13];
    const float* W3 = (const float*)d_in[14]; const float* b3 = (const float*)d_in[15];
    const float* g3 = (const float*)d_in[16]; const float* bt3 = (const float*)d_in[17];
    const float* Wm = (const float*)d_in[18]; const float* bm = (const float*)d_in[19];

    char* wb = (char*)d_ws;
    size_t off = 0;
    auto alloc = [&](size_t nwords) {
        void* p = wb + off; off += ((nwords + 3) & ~(size_t)3) * 4; return p;
    };
    // --- zero-region ---
    int* degi1 = (int*)alloc(N);   int* fill1 = (int*)alloc(N);
    int* degi2 = (int*)alloc(C1n); int* fill2 = (int*)alloc(C1n);
    int* degi3 = (int*)alloc(C2n); int* fill3 = (int*)alloc(C2n);
    float* st1 = (float*)alloc(128); float* st2 = (float*)alloc(128); float* st3 = (float*)alloc(128);
    float* xp1 = (float*)alloc((size_t)C1n * FIN); float* cnt1 = (float*)alloc(C1n);
    float* xp2 = (float*)alloc((size_t)C2n * FIN); float* cnt2 = (float*)alloc(C2n);
    size_t zero_bytes = off;
    // --- fully-overwritten region ---
    int* rp1 = (int*)alloc(N + 1);   int2* cv1 = (int2*)alloc(2 * (size_t)E);
    int* rp2 = (int*)alloc(C1n + 1); int2* cv2 = (int2*)alloc(2 * (size_t)E1);
    int* rp3 = (int*)alloc(C2n + 1); int2* cv3 = (int2*)alloc(2 * (size_t)E2);
    float* dis1 = (float*)alloc(N); float* dis2 = (float*)alloc(C1n); float* dis3 = (float*)alloc(C2n);
    int* bsum = (int*)alloc(1024);
    float* scsh1 = (float*)alloc(128); float* scsh2 = (float*)alloc(128); float* scsh3 = (float*)alloc(128);
    float* B1_0 = (float*)alloc((size_t)N * FIN);   float* B1_1 = (float*)alloc((size_t)N * FIN);
    float* B2_0 = (float*)alloc((size_t)C1n * FIN); float* B2_1 = (float*)alloc((size_t)C1n * FIN);
    float* B3_0 = (float*)alloc((size_t)C2n * FIN); float* B3_1 = (float*)alloc((size_t)C2n * FIN);
    float* acc1 = (float*)alloc((size_t)N * NHID);
    float* acc2 = (float*)alloc((size_t)C1n * NHID);
    float* acc3 = (float*)alloc((size_t)C2n * NHID);
    if (off > ws_size) return;  // fail visibly if ws too small

    hipMemsetAsync(d_ws, 0, zero_bytes, stream);

    const int T = 256;
    auto cdiv = [](int a, int b) { return (a + b - 1) / b; };

    auto branch = [&](const float* xin, int n, const int* e, int Ecnt,
                      const float* W, const float* bb, int* degi, int* fill, float* dis,
                      int* rp, int2* cv, float* B0, float* Bb1, float* acc, float* st) {
        int ge = cdiv(Ecnt, T), gn = cdiv(n, T);
        int nb = cdiv(n + 1, 256);
        int gg = cdiv(n, 64);        // gemv: one 64-node tile per block
        int gp = cdiv(n * 6, T);     // propg: thread per (node, chunk)
        const int WSZ = FIN * NHID;
        // CSR build
        k_hist<<<ge, T, 0, stream>>>(e, Ecnt, degi);
        k_dis<<<gn, T, 0, stream>>>(degi, dis, n);
        k_scan_local<<<nb, 256, 0, stream>>>(degi, n, rp, bsum);
        k_scan_bsum<<<1, 256, 0, stream>>>(bsum, nb);
        k_scan_add<<<nb, 256, 0, stream>>>(rp, bsum, n);
        k_fill<<<ge, T, 0, stream>>>(e, Ecnt, dis, rp, fill, cv);
        // Tx1 = P(x) -> B0
        k_propg<<<gp, T, 0, stream>>>(rp, cv, 1.0f, xin, nullptr, B0, n);
        // acc = b + x@W0 + Tx1@W1
        k_gemv2<<<gg, T, 0, stream>>>(xin, B0, W, W + WSZ, bb, acc, nullptr, n);
        // Tx2 = 2P(Tx1) - x -> Bb1
        k_propg<<<gp, T, 0, stream>>>(rp, cv, 2.0f, B0, xin, Bb1, n);
        // Tx3 = 2P(Tx2) - Tx1 -> B0 (in place over prev)
        k_propg<<<gp, T, 0, stream>>>(rp, cv, 2.0f, Bb1, B0, B0, n);
        // acc += Tx2@W2 + Tx3@W3
        k_gemv2<<<gg, T, 0, stream>>>(Bb1, B0, W + 2 * WSZ, W + 3 * WSZ, nullptr, acc, nullptr, n);
        // Tx4 = 2P(Tx3) - Tx2 -> Bb1
        k_propg<<<gp, T, 0, stream>>>(rp, cv, 2.0f, B0, Bb1, Bb1, n);
        // Tx5 = 2P(Tx4) - Tx3 -> B0
        k_propg<<<gp, T, 0, stream>>>(rp, cv, 2.0f, Bb1, B0, B0, n);
        // acc += Tx4@W4 + Tx5@W5 (+BN stats)
        k_gemv2<<<gg, T, 0, stream>>>(Bb1, B0, W + 4 * WSZ, W + 5 * WSZ, nullptr, acc, st, n);
    };

    // branch 1: full graph
    branch(x, N, ei, E, W1, b1, degi1, fill1, dis1, rp1, cv1, B1_0, B1_1, acc1, st1);
    // branch 2
    k_scatter<<<cdiv(N * FIN, T), T, 0, stream>>>(x, cl1, N, xp1, cnt1);
    k_divcnt<<<cdiv(C1n * FIN, T), T, 0, stream>>>(xp1, cnt1, C1n);
    branch(xp1, C1n, eic1, E1, W2, b2, degi2, fill2, dis2, rp2, cv2, B2_0, B2_1, acc2, st2);
    // branch 3
    k_scatter<<<cdiv(N * FIN, T), T, 0, stream>>>(x, cl2, N, xp2, cnt2);
    k_divcnt<<<cdiv(C2n * FIN, T), T, 0, stream>>>(xp2, cnt2, C2n);
    branch(xp2, C2n, eic2, E2, W3, b3, degi3, fill3, dis3, rp3, cv3, B3_0, B3_1, acc3, st3);
    // BN coefficients for all three branches, then fused final mix
    k_bnprep3<<<1, 192, 0, stream>>>(st1, g1, bt1, 1.0f / (float)N,
                                     st2, g2, bt2, 1.0f / (float)C1n,
                                     st3, g3, bt3, 1.0f / (float)C2n,
                                     scsh1, scsh2, scsh3);
    k_final<<<cdiv(N, T), T, 0, stream>>>(acc1, scsh1, acc2, scsh2, cl1,
                                          acc3, scsh3, cl2,
                                          x, Wm, bm, (float*)d_out, N);
}